// Round 1
// baseline (315.276 us; speedup 1.0000x reference)
//
#include <hip/hip_runtime.h>
#include <hip/hip_bf16.h>

#define IMG 28
#define OHW 26
#define NPIX (OHW * OHW)   // 676
#define KPAD 704           // 22 * 32
#define NH 200
#define NHPAD 224          // 14 * 16
#define NOUT 10
#define MT 32              // images per block
#define ASTRIDE 712        // bf16 elems per LDS A row (704 + 8 pad -> free 2-way conflicts)
#define HSTRIDE 208        // fp32 elems per LDS h row

typedef __attribute__((ext_vector_type(8))) short bf16x8;
typedef __attribute__((ext_vector_type(4))) float f32x4;

// --- cast w0 (200x676 fp32) -> zero-padded 224x704 bf16 in workspace ---
__global__ void cast_w0_kernel(const float* __restrict__ w0,
                               __hip_bfloat16* __restrict__ w0b) {
    int idx = blockIdx.x * blockDim.x + threadIdx.x;
    if (idx >= NHPAD * KPAD) return;
    int n = idx / KPAD;
    int k = idx - n * KPAD;
    float v = (n < NH && k < NPIX) ? w0[n * NPIX + k] : 0.0f;
    w0b[idx] = __float2bfloat16(v);
}

__global__ __launch_bounds__(256, 3) void fused_mlp_kernel(
    const float* __restrict__ x,       // [32768, 784]
    const float* __restrict__ cw,      // [3,3]
    const __hip_bfloat16* __restrict__ w0b, // [224, 704] bf16, padded
    const float* __restrict__ b0,      // [200]
    const float* __restrict__ w1,      // [10, 200]
    const float* __restrict__ b1,      // [10]
    float* __restrict__ out)           // [32768, 10]
{
    __shared__ __align__(16) char lds_raw[MT * ASTRIDE * 2]; // 45568 B
    __hip_bfloat16* A = (__hip_bfloat16*)lds_raw;            // [MT][ASTRIDE] bf16
    float* H = (float*)lds_raw;                              // [MT][HSTRIDE] fp32 (reuse)

    const int tid = threadIdx.x;
    const int img0 = blockIdx.x * MT;

    const float k00 = cw[0], k01 = cw[1], k02 = cw[2];
    const float k10 = cw[3], k11 = cw[4], k12 = cw[5];
    const float k20 = cw[6], k21 = cw[7], k22 = cw[8];

    // ---- zero the K pad region (cols 676..711) ----
    for (int idx = tid; idx < MT * (ASTRIDE - NPIX); idx += 256) {
        int i = idx / (ASTRIDE - NPIX);
        int c = idx - i * (ASTRIDE - NPIX);
        ((unsigned short*)A)[i * ASTRIDE + NPIX + c] = 0;
    }

    // ---- conv 3x3 valid, fp32 VALU, store bf16 to LDS ----
    for (int i = 0; i < MT; ++i) {
        const float* xi = x + (size_t)(img0 + i) * (IMG * IMG);
        for (int p = tid; p < NPIX; p += 256) {
            int r = p / OHW;
            int c = p - r * OHW;
            const float* xp = xi + r * IMG + c;
            float acc = xp[0]  * k00 + xp[1]  * k01 + xp[2]  * k02
                      + xp[28] * k10 + xp[29] * k11 + xp[30] * k12
                      + xp[56] * k20 + xp[57] * k21 + xp[58] * k22;
            A[i * ASTRIDE + p] = __float2bfloat16(acc);
        }
    }
    __syncthreads();

    // ---- FC0 via MFMA 16x16x32 bf16 ----
    const int wave = tid >> 6;          // 0..3
    const int lane = tid & 63;
    const int lm   = lane & 15;         // m (A) / n (B) / col (D) within tile
    const int quad = lane >> 4;         // 0..3
    const int mt   = wave >> 1;         // m-tile 0..1
    const int nt0  = (wave & 1) * 7;    // 7 n-tiles per wave (14 total, n padded to 224)

    f32x4 acc[7];
#pragma unroll
    for (int t = 0; t < 7; ++t) acc[t] = (f32x4){0.f, 0.f, 0.f, 0.f};

    const __hip_bfloat16* a_base = A + (mt * 16 + lm) * ASTRIDE + quad * 8;
    const __hip_bfloat16* b_base = w0b + quad * 8;

    for (int k0 = 0; k0 < KPAD; k0 += 32) {
        bf16x8 afrag = *(const bf16x8*)(a_base + k0);
#pragma unroll
        for (int t = 0; t < 7; ++t) {
            int n = (nt0 + t) * 16 + lm;
            bf16x8 bfrag = *(const bf16x8*)(b_base + (size_t)n * KPAD + k0);
            acc[t] = __builtin_amdgcn_mfma_f32_16x16x32_bf16(afrag, bfrag, acc[t], 0, 0, 0);
        }
    }
    __syncthreads(); // all waves done reading A before H overwrites it

    // ---- epilogue: h = relu(acc + b0) -> LDS ----
#pragma unroll
    for (int t = 0; t < 7; ++t) {
        int n = (nt0 + t) * 16 + lm;
        if (n < NH) {
            float bv = b0[n];
#pragma unroll
            for (int r = 0; r < 4; ++r) {
                int m = mt * 16 + quad * 4 + r;
                float v = acc[t][r] + bv;
                H[m * HSTRIDE + n] = v > 0.f ? v : 0.f;
            }
        }
    }
    __syncthreads();

    // ---- FC1: out = h @ w1.T + b1 (fp32 VALU) ----
    for (int idx = tid; idx < MT * NOUT; idx += 256) {
        int i = idx / NOUT;
        int j = idx - i * NOUT;
        const float4* hrow = (const float4*)(H + i * HSTRIDE);
        const float4* wrow = (const float4*)(w1 + j * NH);
        float s = b1[j];
        float4 accv = {0.f, 0.f, 0.f, 0.f};
#pragma unroll 5
        for (int n = 0; n < NH / 4; ++n) {
            float4 h4 = hrow[n];
            float4 w4 = wrow[n];
            accv.x += h4.x * w4.x;
            accv.y += h4.y * w4.y;
            accv.z += h4.z * w4.z;
            accv.w += h4.w * w4.w;
        }
        s += (accv.x + accv.y) + (accv.z + accv.w);
        out[(size_t)(img0 + i) * NOUT + j] = s;
    }
}

extern "C" void kernel_launch(void* const* d_in, const int* in_sizes, int n_in,
                              void* d_out, int out_size, void* d_ws, size_t ws_size,
                              hipStream_t stream) {
    const float* x   = (const float*)d_in[0];
    const float* cw  = (const float*)d_in[1];
    const float* w0  = (const float*)d_in[2];
    const float* b0  = (const float*)d_in[3];
    const float* w1  = (const float*)d_in[4];
    const float* b1  = (const float*)d_in[5];
    float* out = (float*)d_out;

    __hip_bfloat16* w0b = (__hip_bfloat16*)d_ws; // 224*704*2 = 315392 B

    int cast_elems = NHPAD * KPAD;
    cast_w0_kernel<<<(cast_elems + 255) / 256, 256, 0, stream>>>(w0, w0b);

    int nblocks = 32768 / MT; // 1024
    fused_mlp_kernel<<<nblocks, 256, 0, stream>>>(x, cw, w0b, b0, w1, b1, out);
}

// Round 2
// 208.677 us; speedup vs baseline: 1.5108x; 1.5108x over previous
//
#include <hip/hip_runtime.h>
#include <hip/hip_bf16.h>

#define IMG 28
#define OHW 26
#define NPIX (OHW * OHW)   // 676
#define KPAD 704           // 22 * 32
#define NH 200
#define NHPAD 224          // 14 * 16
#define NOUT 10
#define MT 32              // images per block
#define ASTRIDE 712        // bf16 elems per LDS A row (704 + 8 pad)
#define HSTRIDE 208        // fp32 elems per LDS h row

typedef __attribute__((ext_vector_type(8))) short bf16x8;
typedef __attribute__((ext_vector_type(4))) float f32x4;

static __device__ __forceinline__ unsigned short bf16_bits(float v) {
    __hip_bfloat16 b = __float2bfloat16(v);
    return *(unsigned short*)&b;
}

// --- cast w0 (200x676 fp32) -> zero-padded 224x704 bf16 in workspace ---
__global__ void cast_w0_kernel(const float* __restrict__ w0,
                               __hip_bfloat16* __restrict__ w0b) {
    int idx = blockIdx.x * blockDim.x + threadIdx.x;
    if (idx >= NHPAD * KPAD) return;
    int n = idx / KPAD;
    int k = idx - n * KPAD;
    float v = (n < NH && k < NPIX) ? w0[n * NPIX + k] : 0.0f;
    w0b[idx] = __float2bfloat16(v);
}

// FC0 inner loop, NT n-tiles per wave, B-frag reused across both m-tiles.
template <int NT>
static __device__ __forceinline__ void fc0_loop(
    const __hip_bfloat16* __restrict__ a0,   // A row base, m-tile 0 (incl quad*8)
    const __hip_bfloat16* __restrict__ a1,   // A row base, m-tile 1
    const __hip_bfloat16* __restrict__ bbase,// w0b + (ntbase*16+lm)*KPAD + quad*8
    f32x4 acc[2][4])
{
    for (int k0 = 0; k0 < KPAD; k0 += 32) {
        bf16x8 af0 = *(const bf16x8*)(a0 + k0);
        bf16x8 af1 = *(const bf16x8*)(a1 + k0);
#pragma unroll
        for (int t = 0; t < NT; ++t) {
            bf16x8 bf = *(const bf16x8*)(bbase + (size_t)t * 16 * KPAD + k0);
            acc[0][t] = __builtin_amdgcn_mfma_f32_16x16x32_bf16(af0, bf, acc[0][t], 0, 0, 0);
            acc[1][t] = __builtin_amdgcn_mfma_f32_16x16x32_bf16(af1, bf, acc[1][t], 0, 0, 0);
        }
    }
}

__global__ __launch_bounds__(256, 3) void fused_mlp_kernel(
    const float* __restrict__ x,       // [32768, 784]
    const float* __restrict__ cw,      // [3,3]
    const __hip_bfloat16* __restrict__ w0b, // [224, 704] bf16, padded
    const float* __restrict__ b0,      // [200]
    const float* __restrict__ w1,      // [10, 200]
    const float* __restrict__ b1,      // [10]
    float* __restrict__ out)           // [32768, 10]
{
    __shared__ __align__(16) char lds_raw[MT * ASTRIDE * 2]; // 45568 B
    __hip_bfloat16* A = (__hip_bfloat16*)lds_raw;            // [MT][ASTRIDE] bf16
    float* H = (float*)lds_raw;                              // [MT][HSTRIDE] fp32 (reuse)

    const int tid = threadIdx.x;
    const int img0 = blockIdx.x * MT;

    const float k00 = cw[0], k01 = cw[1], k02 = cw[2];
    const float k10 = cw[3], k11 = cw[4], k12 = cw[5];
    const float k20 = cw[6], k21 = cw[7], k22 = cw[8];

    // ---- zero the K pad region (cols 676..711) ----
    for (int idx = tid; idx < MT * (ASTRIDE - NPIX); idx += 256) {
        int i = idx / (ASTRIDE - NPIX);
        int c = idx - i * (ASTRIDE - NPIX);
        ((unsigned short*)A)[i * ASTRIDE + NPIX + c] = 0;
    }

    // ---- conv 3x3 valid: one task = (image, output row); float4 row loads ----
    for (int task = tid; task < MT * OHW; task += 256) {
        int img  = task / OHW;
        int orow = task - img * OHW;
        const float* base = x + (size_t)(img0 + img) * (IMG * IMG) + orow * IMG;

        float4 r0[7], r1[7], r2[7];
#pragma unroll
        for (int j = 0; j < 7; ++j) {
            r0[j] = ((const float4*)base)[j];
            r1[j] = ((const float4*)(base + IMG))[j];
            r2[j] = ((const float4*)(base + 2 * IMG))[j];
        }
        const float* a0r = (const float*)r0;
        const float* a1r = (const float*)r1;
        const float* a2r = (const float*)r2;

        unsigned short obits[OHW];
#pragma unroll
        for (int c = 0; c < OHW; ++c) {
            float acc = a0r[c] * k00 + a0r[c + 1] * k01 + a0r[c + 2] * k02
                      + a1r[c] * k10 + a1r[c + 1] * k11 + a1r[c + 2] * k12
                      + a2r[c] * k20 + a2r[c + 1] * k21 + a2r[c + 2] * k22;
            obits[c] = bf16_bits(acc);
        }
        // pack pairs -> 13 dword LDS writes (dst is 4B aligned: orow*26*2 = 52B stride)
        unsigned* dst = (unsigned*)(A + img * ASTRIDE + orow * OHW);
#pragma unroll
        for (int c2 = 0; c2 < 13; ++c2) {
            dst[c2] = (unsigned)obits[2 * c2] | ((unsigned)obits[2 * c2 + 1] << 16);
        }
    }
    __syncthreads();

    // ---- FC0 via MFMA 16x16x32 bf16; waves own disjoint n-tiles {4,4,3,3} ----
    const int wave = tid >> 6;
    const int lane = tid & 63;
    const int lm   = lane & 15;
    const int quad = lane >> 4;
    const int ntbase = (wave < 2) ? wave * 4 : 8 + (wave - 2) * 3;
    const int ntn    = (wave < 2) ? 4 : 3;

    f32x4 acc[2][4];
#pragma unroll
    for (int m = 0; m < 2; ++m)
#pragma unroll
        for (int t = 0; t < 4; ++t) acc[m][t] = (f32x4){0.f, 0.f, 0.f, 0.f};

    {
        const __hip_bfloat16* a0 = A + (0 * 16 + lm) * ASTRIDE + quad * 8;
        const __hip_bfloat16* a1 = A + (1 * 16 + lm) * ASTRIDE + quad * 8;
        const __hip_bfloat16* bb = w0b + (size_t)(ntbase * 16 + lm) * KPAD + quad * 8;
        if (wave < 2) fc0_loop<4>(a0, a1, bb, acc);
        else          fc0_loop<3>(a0, a1, bb, acc);
    }
    __syncthreads(); // all waves done reading A before H overwrites it

    // ---- epilogue: h = relu(acc + b0) -> LDS ----
#pragma unroll
    for (int t = 0; t < 4; ++t) {
        if (t < ntn) {
            int n = (ntbase + t) * 16 + lm;
            if (n < NH) {
                float bv = b0[n];
#pragma unroll
                for (int m = 0; m < 2; ++m) {
#pragma unroll
                    for (int r = 0; r < 4; ++r) {
                        int mm = m * 16 + quad * 4 + r;
                        float v = acc[m][t][r] + bv;
                        H[mm * HSTRIDE + n] = v > 0.f ? v : 0.f;
                    }
                }
            }
        }
    }
    __syncthreads();

    // ---- FC1: out = h @ w1.T + b1 (fp32 VALU) ----
    for (int idx = tid; idx < MT * NOUT; idx += 256) {
        int i = idx / NOUT;
        int j = idx - i * NOUT;
        const float4* hrow = (const float4*)(H + i * HSTRIDE);
        const float4* wrow = (const float4*)(w1 + j * NH);
        float s = b1[j];
        float4 accv = {0.f, 0.f, 0.f, 0.f};
#pragma unroll 5
        for (int n = 0; n < NH / 4; ++n) {
            float4 h4 = hrow[n];
            float4 w4 = wrow[n];
            accv.x += h4.x * w4.x;
            accv.y += h4.y * w4.y;
            accv.z += h4.z * w4.z;
            accv.w += h4.w * w4.w;
        }
        s += (accv.x + accv.y) + (accv.z + accv.w);
        out[(size_t)(img0 + i) * NOUT + j] = s;
    }
}

extern "C" void kernel_launch(void* const* d_in, const int* in_sizes, int n_in,
                              void* d_out, int out_size, void* d_ws, size_t ws_size,
                              hipStream_t stream) {
    const float* x   = (const float*)d_in[0];
    const float* cw  = (const float*)d_in[1];
    const float* w0  = (const float*)d_in[2];
    const float* b0  = (const float*)d_in[3];
    const float* w1  = (const float*)d_in[4];
    const float* b1  = (const float*)d_in[5];
    float* out = (float*)d_out;

    __hip_bfloat16* w0b = (__hip_bfloat16*)d_ws; // 224*704*2 = 315392 B

    int cast_elems = NHPAD * KPAD;
    cast_w0_kernel<<<(cast_elems + 255) / 256, 256, 0, stream>>>(w0, w0b);

    int nblocks = 32768 / MT; // 1024
    fused_mlp_kernel<<<nblocks, 256, 0, stream>>>(x, cw, w0b, b0, w1, b1, out);
}